// Round 8
// baseline (461.889 us; speedup 1.0000x reference)
//
#include <hip/hip_runtime.h>

// GCN 2-layer forward, MI355X. Round 7 (resubmit after infra timeout):
// deg-atomics fused into gemm1 (hidden under FMA work), 4x replicated counters
// (line-contention dilution), atomic-free CSR place + G-rescale fused kernel,
// dinv derived from rowptr. N=100000, E=1600000, D=128.

#define NN 100000
#define NE 1600000
#define DD 128
#define SCAN_NB 391   // ceil(NN/256); level-1 scan block covers 256 nodes
#define GEMM_NB 1563  // ceil(NN/64); also edge-slab count (1024 edges/block)
#define CSR_NB 6250   // NE/256 exact
#define SCALE_NB 3125 // NN/32 exact

// bf16 helpers (round-to-nearest-even)
__device__ __forceinline__ unsigned f2bf(float f) {
  unsigned u = __float_as_uint(f);
  return (u + 0x7fffu + ((u >> 16) & 1u)) >> 16;
}
__device__ __forceinline__ unsigned pack2(float lo, float hi) {
  return f2bf(lo) | (f2bf(hi) << 16);
}
__device__ __forceinline__ unsigned scale2(unsigned u, float s) {
  float lo = __uint_as_float(u << 16) * s;
  float hi = __uint_as_float(u & 0xffff0000u) * s;
  return pack2(lo, hi);
}

__global__ __launch_bounds__(256) void zero_i32(int* __restrict__ p, int n) {
  int i = blockIdx.x * 256 + threadIdx.x;
  if (i < n) p[i] = 0;
}

// ---------------- fused GEMM1 + degree/rank ----------------
// gemm: 64-row x 128-col tile/block, G = bf16(X@W) UNSCALED.
// edges: block b handles edges [b*1024, b*1024+1024); 4/thread; replica r=(t+i)&3.
__global__ __launch_bounds__(256) void gemm_deg(const float* __restrict__ X,
                                                const float* __restrict__ W,
                                                const int* __restrict__ edst,
                                                int* __restrict__ cntR,
                                                int* __restrict__ rank,
                                                unsigned short* __restrict__ G) {
  const int t = threadIdx.x;
  const int b = blockIdx.x;

  // ---- issue degree atomics first; returns consumed only at kernel end ----
  int myrank[4];
  const int eb = b * 1024;
#pragma unroll
  for (int i = 0; i < 4; ++i) {
    int e = eb + i * 256 + t;
    if (e < NE) {
      int d = edst[e];
      int r = (t + i) & 3;
      int loc = atomicAdd(&cntR[r * NN + d], 1);
      myrank[i] = (loc << 2) | r;
    }
  }

  // ---- gemm ----
  __shared__ float ws2[32][128];
  __shared__ float xs[64][36];
  const int tx = t & 15;
  const int ty = t >> 4;
  const int row0 = b * 64;
  float acc[4][8];
#pragma unroll
  for (int i = 0; i < 4; ++i)
#pragma unroll
    for (int j = 0; j < 8; ++j) acc[i][j] = 0.f;

  for (int kc = 0; kc < 128; kc += 32) {
#pragma unroll
    for (int i = 0; i < 4; ++i) {
      int idx = i * 256 + t;
      int kk = idx >> 5;
      int c4 = idx & 31;
      *(float4*)&ws2[kk][c4 * 4] = *(const float4*)&W[(kc + kk) * 128 + c4 * 4];
    }
#pragma unroll
    for (int i = 0; i < 2; ++i) {
      int idx = i * 256 + t;
      int r = idx >> 3;
      int c4 = idx & 7;
      int grow = row0 + r;
      if (grow > NN - 1) grow = NN - 1;
      *(float4*)&xs[r][c4 * 4] = *(const float4*)&X[grow * 128 + kc + c4 * 4];
    }
    __syncthreads();
#pragma unroll
    for (int kk = 0; kk < 32; kk += 4) {
      float4 a0 = *(float4*)&xs[ty * 4 + 0][kk];
      float4 a1 = *(float4*)&xs[ty * 4 + 1][kk];
      float4 a2 = *(float4*)&xs[ty * 4 + 2][kk];
      float4 a3 = *(float4*)&xs[ty * 4 + 3][kk];
#pragma unroll
      for (int j = 0; j < 4; ++j) {
        float4 b0 = *(float4*)&ws2[kk + j][tx * 4];
        float4 b1 = *(float4*)&ws2[kk + j][64 + tx * 4];
        float a[4] = {j == 0 ? a0.x : j == 1 ? a0.y : j == 2 ? a0.z : a0.w,
                      j == 0 ? a1.x : j == 1 ? a1.y : j == 2 ? a1.z : a1.w,
                      j == 0 ? a2.x : j == 1 ? a2.y : j == 2 ? a2.z : a2.w,
                      j == 0 ? a3.x : j == 1 ? a3.y : j == 2 ? a3.z : a3.w};
#pragma unroll
        for (int i = 0; i < 4; ++i) {
          acc[i][0] += a[i] * b0.x;
          acc[i][1] += a[i] * b0.y;
          acc[i][2] += a[i] * b0.z;
          acc[i][3] += a[i] * b0.w;
          acc[i][4] += a[i] * b1.x;
          acc[i][5] += a[i] * b1.y;
          acc[i][6] += a[i] * b1.z;
          acc[i][7] += a[i] * b1.w;
        }
      }
    }
    __syncthreads();
  }
#pragma unroll
  for (int i = 0; i < 4; ++i) {
    int row = row0 + ty * 4 + i;
    if (row < NN) {
      uint2 p0 = make_uint2(pack2(acc[i][0], acc[i][1]), pack2(acc[i][2], acc[i][3]));
      uint2 p1 = make_uint2(pack2(acc[i][4], acc[i][5]), pack2(acc[i][6], acc[i][7]));
      *(uint2*)&G[row * 128 + tx * 4] = p0;
      *(uint2*)&G[row * 128 + 64 + tx * 4] = p1;
    }
  }

  // ---- write ranks (atomic returns have long since landed) ----
#pragma unroll
  for (int i = 0; i < 4; ++i) {
    int e = eb + i * 256 + t;
    if (e < NE) rank[e] = myrank[i];
  }
}

// ---------------- scan over NN*4 replica counters (node-major flat order) ----------------

__global__ __launch_bounds__(256) void scan_l1(const int* __restrict__ cntR,
                                               int* __restrict__ bsum) {
  __shared__ int s[256];
  int t = threadIdx.x;
  int node = blockIdx.x * 256 + t;
  int sum = 0;
  if (node < NN) {
#pragma unroll
    for (int r = 0; r < 4; ++r) sum += cntR[r * NN + node];
  }
  s[t] = sum;
  __syncthreads();
  for (int off = 128; off > 0; off >>= 1) {
    if (t < off) s[t] += s[t + off];
    __syncthreads();
  }
  if (t == 0) bsum[blockIdx.x] = s[0];
}

__global__ __launch_bounds__(512) void scan_partials(int* __restrict__ bsum) {
  __shared__ int s[512];
  int t = threadIdx.x;
  int v = (t < SCAN_NB) ? bsum[t] : 0;
  s[t] = v;
  __syncthreads();
  for (int off = 1; off < 512; off <<= 1) {
    int a = (t >= off) ? s[t - off] : 0;
    __syncthreads();
    s[t] += a;
    __syncthreads();
  }
  if (t < SCAN_NB) bsum[t] = s[t] - v;  // exclusive
}

// writes off[node*4 + r] (exclusive prefix over flat (node,r)); off[NN*4] = NE
__global__ __launch_bounds__(256) void scan_l2(const int* __restrict__ cntR,
                                               const int* __restrict__ bsum,
                                               int* __restrict__ offp) {
  __shared__ int s[256];
  int t = threadIdx.x;
  int node = blockIdx.x * 256 + t;
  int v[4] = {0, 0, 0, 0};
  if (node < NN) {
#pragma unroll
    for (int r = 0; r < 4; ++r) v[r] = cntR[r * NN + node];
  }
  int tot = v[0] + v[1] + v[2] + v[3];
  s[t] = tot;
  __syncthreads();
  for (int o = 1; o < 256; o <<= 1) {
    int a = (t >= o) ? s[t - o] : 0;
    __syncthreads();
    s[t] += a;
    __syncthreads();
  }
  int base = bsum[blockIdx.x] + s[t] - tot;  // exclusive prefix for this node
  if (node < NN) {
    int acc = base;
#pragma unroll
    for (int r = 0; r < 4; ++r) {
      offp[node * 4 + r] = acc;
      acc += v[r];
    }
    if (node == NN - 1) offp[NN * 4] = acc;  // == NE
  }
}

// ---------------- fused CSR place (no atomics) + G *= dinv rescale ----------------

__global__ __launch_bounds__(256) void csr_scale(const int* __restrict__ esrc,
                                                 const int* __restrict__ edst,
                                                 const int* __restrict__ rank,
                                                 const int* __restrict__ offp,
                                                 int* __restrict__ col,
                                                 unsigned short* __restrict__ G) {
  int b = blockIdx.x;
  int t = threadIdx.x;
  if (b < CSR_NB) {
    int e = b * 256 + t;  // exact NE coverage
    int d = edst[e];
    int rk = rank[e];
    int pos = offp[d * 4 + (rk & 3)] + (rk >> 2);
    col[pos] = esrc[e];
  } else {
    int sb = b - CSR_NB;            // 0..3124
    int base = sb * 4096 + t * 16;  // 16 bf16 per thread, single row each
    int row = base >> 7;
    int d0 = offp[row * 4];
    int d1 = offp[row * 4 + 4];
    float di = rsqrtf((float)(d1 - d0) + 1.0f);
    uint4* p = (uint4*)&G[base];
#pragma unroll
    for (int q = 0; q < 2; ++q) {
      uint4 u = p[q];
      u.x = scale2(u.x, di);
      u.y = scale2(u.y, di);
      u.z = scale2(u.z, di);
      u.w = scale2(u.w, di);
      p[q] = u;
    }
  }
}

// ---------------- aggregate: out = relu(di*(G_i + sum_j G_j) + b), G prescaled by dinv ----------------

__global__ __launch_bounds__(256) void aggregate(const unsigned short* __restrict__ G,
                                                 const int* __restrict__ offp,
                                                 const int* __restrict__ col,
                                                 const float* __restrict__ bias,
                                                 float* __restrict__ out) {
  int gid = blockIdx.x * 256 + threadIdx.x;  // NN*32 threads, exact
  int node = gid >> 5;
  int lane = gid & 31;
  const int off = lane * 4;

  int e = offp[node * 4];
  int e1 = offp[node * 4 + 4];
  float di = rsqrtf((float)(e1 - e) + 1.0f);

  uint2 us = *(const uint2*)&G[node * DD + off];
  float4 acc;
  acc.x = __uint_as_float(us.x << 16);
  acc.y = __uint_as_float(us.x & 0xffff0000u);
  acc.z = __uint_as_float(us.y << 16);
  acc.w = __uint_as_float(us.y & 0xffff0000u);

  for (; e + 3 < e1; e += 4) {
    int s0 = col[e + 0];
    int s1 = col[e + 1];
    int s2 = col[e + 2];
    int s3 = col[e + 3];
    uint2 u0 = *(const uint2*)&G[s0 * DD + off];
    uint2 u1 = *(const uint2*)&G[s1 * DD + off];
    uint2 u2 = *(const uint2*)&G[s2 * DD + off];
    uint2 u3 = *(const uint2*)&G[s3 * DD + off];
    acc.x += __uint_as_float(u0.x << 16);
    acc.y += __uint_as_float(u0.x & 0xffff0000u);
    acc.z += __uint_as_float(u0.y << 16);
    acc.w += __uint_as_float(u0.y & 0xffff0000u);
    acc.x += __uint_as_float(u1.x << 16);
    acc.y += __uint_as_float(u1.x & 0xffff0000u);
    acc.z += __uint_as_float(u1.y << 16);
    acc.w += __uint_as_float(u1.y & 0xffff0000u);
    acc.x += __uint_as_float(u2.x << 16);
    acc.y += __uint_as_float(u2.x & 0xffff0000u);
    acc.z += __uint_as_float(u2.y << 16);
    acc.w += __uint_as_float(u2.y & 0xffff0000u);
    acc.x += __uint_as_float(u3.x << 16);
    acc.y += __uint_as_float(u3.x & 0xffff0000u);
    acc.z += __uint_as_float(u3.y << 16);
    acc.w += __uint_as_float(u3.y & 0xffff0000u);
  }
  for (; e < e1; ++e) {
    int s0 = col[e];
    uint2 u0 = *(const uint2*)&G[s0 * DD + off];
    acc.x += __uint_as_float(u0.x << 16);
    acc.y += __uint_as_float(u0.x & 0xffff0000u);
    acc.z += __uint_as_float(u0.y << 16);
    acc.w += __uint_as_float(u0.y & 0xffff0000u);
  }

  float4 bv = *(const float4*)&bias[off];
  acc.x = fmaxf(acc.x * di + bv.x, 0.f);
  acc.y = fmaxf(acc.y * di + bv.y, 0.f);
  acc.z = fmaxf(acc.z * di + bv.z, 0.f);
  acc.w = fmaxf(acc.w * di + bv.w, 0.f);
  *(float4*)&out[node * DD + off] = acc;
}

// ---------------- GEMM (layer 2): G = bf16( dinv * (X@W) ), dinv from offp ----------------

__global__ __launch_bounds__(256) void gemm128(const float* __restrict__ X,
                                               const float* __restrict__ W,
                                               const int* __restrict__ offp,
                                               unsigned short* __restrict__ G) {
  __shared__ float ws2[32][128];
  __shared__ float xs[64][36];
  const int t = threadIdx.x;
  const int tx = t & 15;
  const int ty = t >> 4;
  const int row0 = blockIdx.x * 64;
  float acc[4][8];
#pragma unroll
  for (int i = 0; i < 4; ++i)
#pragma unroll
    for (int j = 0; j < 8; ++j) acc[i][j] = 0.f;

  for (int kc = 0; kc < 128; kc += 32) {
#pragma unroll
    for (int i = 0; i < 4; ++i) {
      int idx = i * 256 + t;
      int kk = idx >> 5;
      int c4 = idx & 31;
      *(float4*)&ws2[kk][c4 * 4] = *(const float4*)&W[(kc + kk) * 128 + c4 * 4];
    }
#pragma unroll
    for (int i = 0; i < 2; ++i) {
      int idx = i * 256 + t;
      int r = idx >> 3;
      int c4 = idx & 7;
      int grow = row0 + r;
      if (grow > NN - 1) grow = NN - 1;
      *(float4*)&xs[r][c4 * 4] = *(const float4*)&X[grow * 128 + kc + c4 * 4];
    }
    __syncthreads();
#pragma unroll
    for (int kk = 0; kk < 32; kk += 4) {
      float4 a0 = *(float4*)&xs[ty * 4 + 0][kk];
      float4 a1 = *(float4*)&xs[ty * 4 + 1][kk];
      float4 a2 = *(float4*)&xs[ty * 4 + 2][kk];
      float4 a3 = *(float4*)&xs[ty * 4 + 3][kk];
#pragma unroll
      for (int j = 0; j < 4; ++j) {
        float4 b0 = *(float4*)&ws2[kk + j][tx * 4];
        float4 b1 = *(float4*)&ws2[kk + j][64 + tx * 4];
        float a[4] = {j == 0 ? a0.x : j == 1 ? a0.y : j == 2 ? a0.z : a0.w,
                      j == 0 ? a1.x : j == 1 ? a1.y : j == 2 ? a1.z : a1.w,
                      j == 0 ? a2.x : j == 1 ? a2.y : j == 2 ? a2.z : a2.w,
                      j == 0 ? a3.x : j == 1 ? a3.y : j == 2 ? a3.z : a3.w};
#pragma unroll
        for (int i = 0; i < 4; ++i) {
          acc[i][0] += a[i] * b0.x;
          acc[i][1] += a[i] * b0.y;
          acc[i][2] += a[i] * b0.z;
          acc[i][3] += a[i] * b0.w;
          acc[i][4] += a[i] * b1.x;
          acc[i][5] += a[i] * b1.y;
          acc[i][6] += a[i] * b1.z;
          acc[i][7] += a[i] * b1.w;
        }
      }
    }
    __syncthreads();
  }
#pragma unroll
  for (int i = 0; i < 4; ++i) {
    int row = row0 + ty * 4 + i;
    if (row < NN) {
      int d0 = offp[row * 4];
      int d1 = offp[row * 4 + 4];
      float di = rsqrtf((float)(d1 - d0) + 1.0f);
      uint2 p0 = make_uint2(pack2(acc[i][0] * di, acc[i][1] * di),
                            pack2(acc[i][2] * di, acc[i][3] * di));
      uint2 p1 = make_uint2(pack2(acc[i][4] * di, acc[i][5] * di),
                            pack2(acc[i][6] * di, acc[i][7] * di));
      *(uint2*)&G[row * 128 + tx * 4] = p0;
      *(uint2*)&G[row * 128 + 64 + tx * 4] = p1;
    }
  }
}

// ---------------- launch ----------------

extern "C" void kernel_launch(void* const* d_in, const int* in_sizes, int n_in,
                              void* d_out, int out_size, void* d_ws, size_t ws_size,
                              hipStream_t stream) {
  const float* x  = (const float*)d_in[0];
  const int*   ei = (const int*)d_in[1];  // [2][NE] int32
  const float* W1 = (const float*)d_in[2];
  const float* b1 = (const float*)d_in[3];
  const float* W2 = (const float*)d_in[4];
  const float* b2 = (const float*)d_in[5];
  float* out = (float*)d_out;

  const int* esrc = ei;
  const int* edst = ei + NE;

  // workspace layout:
  char* w = (char*)d_ws;
  int* cntR = (int*)w;  w += (size_t)(NN * 4) * 4;          // 4 replicas x NN
  int* offp = (int*)w;  w += (size_t)(NN * 4 + 16) * 4;     // NN*4+1 offsets
  int* bsum = (int*)w;  w += 512 * 4;
  int* rank = (int*)w;  w += (size_t)NE * 4;
  int* col  = (int*)w;  w += (size_t)NE * 4;
  unsigned short* G = (unsigned short*)w;                   // NN*DD bf16

  zero_i32<<<GEMM_NB, 256, 0, stream>>>(cntR, NN * 4);

  // layer 1 GEMM + degree count/rank (overlapped in one kernel)
  gemm_deg<<<GEMM_NB, 256, 0, stream>>>(x, W1, edst, cntR, rank, G);

  // scan replicated counters -> offp
  scan_l1<<<SCAN_NB, 256, 0, stream>>>(cntR, bsum);
  scan_partials<<<1, 512, 0, stream>>>(bsum);
  scan_l2<<<SCAN_NB, 256, 0, stream>>>(cntR, bsum, offp);

  // CSR placement + G *= dinv (overlapped in one kernel)
  csr_scale<<<CSR_NB + SCALE_NB, 256, 0, stream>>>(esrc, edst, rank, offp, col, G);

  // layer 1 aggregate
  aggregate<<<NN * 32 / 256, 256, 0, stream>>>(G, offp, col, b1, out);

  // layer 2
  gemm128<<<GEMM_NB, 256, 0, stream>>>(out, W2, offp, G);
  aggregate<<<NN * 32 / 256, 256, 0, stream>>>(G, offp, col, b2, out);
}